// Round 14
// baseline (180.700 us; speedup 1.0000x reference)
//
#include <hip/hip_runtime.h>
#include <hip/hip_bf16.h>

typedef __bf16 bf16x8 __attribute__((ext_vector_type(8)));
typedef float  f32x4  __attribute__((ext_vector_type(4)));
typedef unsigned short ushort_t;

#define NN 468

// wext element offsets (ushort), fragment-major planes (NOT swizzled)
#define W1H 0
#define W1L 8192
#define W2H 16384
#define W2L 49152
#define W3H 81920
#define W3L 114688

// LDS byte offsets — peak 35,736 B -> 4 blocks/CU (32 waves with VGPR<=64)
#define L_LM   0       // 258 f32 = 1032                   (phase A only)
#define L_Y1   8192    // 2 planes x 5120 ushort = 20480   [8192,28672) A..GEMM1
#define L_X1   0       // [68][68] f32 = 18496             [0,18496)  kc loop
#define L_Y2   18496   // 2 planes x 4096 ushort = 16384   [18496,34880) kc loop
#define L_X2   0       // [50][132] f32 = 26400            [0,26400)  nc loop
#define L_Y3   26400   // 2 planes x 2048 ushort = 8192    [26400,34592) k-chunked
#define L_DTAB 34880   // 86 f32 = 344
#define L_POOL 35224   // 128 f32 = 512  (ends 35736)

#define MFMA3(d, ah, al, wh, wl)                                        \
    d = __builtin_amdgcn_mfma_f32_16x16x32_bf16(ah, wh, d, 0, 0, 0);    \
    d = __builtin_amdgcn_mfma_f32_16x16x32_bf16(ah, wl, d, 0, 0, 0);    \
    d = __builtin_amdgcn_mfma_f32_16x16x32_bf16(al, wh, d, 0, 0, 0);

// ---------------------------------------------------------------------------
__device__ __forceinline__ void pack_split4(const float* y,
                                            ushort_t* hdst, ushort_t* ldst) {
    ushort_t h[4], l[4];
    #pragma unroll
    for (int j = 0; j < 4; ++j) {
        __hip_bfloat16 hb = __float2bfloat16(y[j]);
        float hf = __bfloat162float(hb);
        __hip_bfloat16 lb = __float2bfloat16(y[j] - hf);
        h[j] = *(ushort_t*)&hb; l[j] = *(ushort_t*)&lb;
    }
    uint2 hv = make_uint2((unsigned)h[0] | ((unsigned)h[1] << 16),
                          (unsigned)h[2] | ((unsigned)h[3] << 16));
    uint2 lv = make_uint2((unsigned)l[0] | ((unsigned)l[1] << 16),
                          (unsigned)l[2] | ((unsigned)l[3] << 16));
    *(uint2*)hdst = hv;
    *(uint2*)ldst = lv;
}

// unswizzled fragment offset (W planes in global memory)
__device__ __forceinline__ int frag_off(int r, int k, int K16) {
    return (r >> 4) * K16 + (k >> 5) * 512 + ((k >> 3) & 3) * 128
         + (r & 15) * 8 + (k & 7);
}

// swizzled Y-plane offset (LDS): unit' = q*16 + ((r ^ 2q) & 15)
__device__ __forceinline__ int ywoff(int r, int k4, int K16) {
    int q = (k4 >> 3) & 3;
    int u = q * 16 + (((r & 15) ^ (q << 1)) & 15);
    return (r >> 4) * K16 + (k4 >> 5) * 512 + u * 8 + (k4 & 7);
}

// ---------------------------------------------------------------------------
// fused: full 3-layer GCN chain for one (32-row tile, batch) in LDS.
// 512 threads = 8 waves (wm = w&1 over m, wn = w>>1 over n).
// Row frames: Y1/X1 lr1: gr = r0-18+lr1 (0..67)
//             Y2/X2 lr2: gr = r0-9+lr2  (0..49)
//             Y3     lr3: gr = r0+lr3   (0..31)
// Per-wave accumulators: acc1[3][2]=24, acc2[2][4]=32, acc3[2]=8 regs.
// launch_bounds(512,8): VGPR cap 64 (R12 compiled to 64 spill-free) -> with
// 35.8KB LDS, 4 blocks/CU = 32 waves.
// ---------------------------------------------------------------------------
__global__ __launch_bounds__(512, 8) void fused(
    const float* __restrict__ Lm, const ushort_t* __restrict__ wext,
    const float* __restrict__ We, const float* __restrict__ be,
    const float* __restrict__ b1, const float* __restrict__ b2,
    const float* __restrict__ b3, float* __restrict__ partial)
{
    __shared__ __align__(16) char lds[35840];
    float*    lmst = (float*)(lds + L_LM);
    ushort_t* Y1h  = (ushort_t*)(lds + L_Y1);  ushort_t* Y1l = Y1h + 5120;
    float*    X1   = (float*)(lds + L_X1);
    ushort_t* Y2h  = (ushort_t*)(lds + L_Y2);  ushort_t* Y2l = Y2h + 4096;
    float*    X2   = (float*)(lds + L_X2);
    ushort_t* Y3h  = (ushort_t*)(lds + L_Y3);  ushort_t* Y3l = Y3h + 2048;
    float*    dtab = (float*)(lds + L_DTAB);
    float*    pool = (float*)(lds + L_POOL);

    const int tid  = threadIdx.x;
    const int lane = tid & 63;
    const int wave = tid >> 6;            // 0..7
    const int wm = wave & 1, wn = wave >> 1;   // wn in 0..3
    const int l15 = lane & 15, lg = lane >> 4;
    const int lswz = (lane & 48) + (((lane & 15) ^ ((lane >> 4) << 1)) & 15);
    const int rt = blockIdx.x, b = blockIdx.y;
    const int r0 = rt * 32;

    // ---------------- stage: dinv table, landmarks, pool init -------------
    if (tid < 86) {
        int ri = r0 - 27 + tid;
        float dv = 0.f;
        if (ri >= 0 && ri < NN) {
            int lo = ri - 9; if (lo < 0) lo = 0;
            int hi = ri + 9; if (hi > NN - 1) hi = NN - 1;
            dv = 1.0f / sqrtf((float)(hi - lo + 1));
        }
        dtab[tid] = dv;
    }
    if (tid < 258) {
        int g = (r0 - 27) * 3 + tid;
        lmst[tid] = (g >= 0 && g < NN * 3) ? Lm[(size_t)b * (NN * 3) + g] : 0.f;
    }
    if (tid < 128) pool[tid] = 0.f;
    __syncthreads();

    // ---------------- band1 (in-register, encoder fused) -> Y1 -------------
    {
        const int c = tid & 63, s = tid >> 6;      // 8 slices x 9 rows
        const float w0 = We[c], w1 = We[64 + c], w2 = We[128 + c], bk = be[c];
        float z[27];
        #pragma unroll
        for (int j = 0; j < 27; ++j) {
            int li = s * 9 + j;                    // local row in 86-frame
            float v = 0.f;
            if (li < 86) {
                float x = bk + lmst[li*3]*w0 + lmst[li*3+1]*w1 + lmst[li*3+2]*w2;
                v = x * dtab[li];                  // dtab=0 masks OOR rows
            }
            z[j] = v;
        }
        float ws = 0.f;
        #pragma unroll
        for (int j = 0; j < 19; ++j) ws += z[j];
        #pragma unroll
        for (int rr = 0; rr < 9; ++rr) {
            if (rr) ws += z[rr + 18] - z[rr - 1];
            int lr = s * 9 + rr;
            if (lr < 68) {
                float y = ws * dtab[lr + 9];
                __hip_bfloat16 hb = __float2bfloat16(y);
                float hf = __bfloat162float(hb);
                __hip_bfloat16 lb = __float2bfloat16(y - hf);
                int off = ywoff(lr, c, 1024);
                Y1h[off] = *(ushort_t*)&hb;
                Y1l[off] = *(ushort_t*)&lb;
            }
        }
        for (int e = tid; e < 192; e += 512) {     // zero pad rows 68..79
            int off = ywoff(68 + (e >> 4), (e & 15) << 2, 1024);
            *(uint2*)(Y1h + off) = make_uint2(0, 0);
            *(uint2*)(Y1l + off) = make_uint2(0, 0);
        }
    }
    __syncthreads();

    // ---------------- GEMM1: Y1(5 tiles) @ W1 ------------------------------
    // m: wm*3+mt clamped to 4 (tile 4 duplicated, benign); n: ntile = nt*4+wn
    f32x4 acc1[3][2] = {};
    __builtin_amdgcn_s_setprio(1);
    #pragma unroll
    for (int kt = 0; kt < 2; ++kt) {
        bf16x8 a[3][2];
        #pragma unroll
        for (int mt = 0; mt < 3; ++mt) {
            int t = wm*3 + mt; if (t > 4) t = 4;
            int off = t * 1024 + kt * 512 + lswz * 8;
            a[mt][0] = *(const bf16x8*)(Y1h + off);
            a[mt][1] = *(const bf16x8*)(Y1l + off);
        }
        #pragma unroll
        for (int nt = 0; nt < 2; ++nt) {
            int woff = (nt*4 + wn) * 1024 + kt * 512 + lane * 8;
            bf16x8 wh = *(const bf16x8*)(wext + W1H + woff);
            bf16x8 wl = *(const bf16x8*)(wext + W1L + woff);
            #pragma unroll
            for (int mt = 0; mt < 3; ++mt) {
                MFMA3(acc1[mt][nt], a[mt][0], a[mt][1], wh, wl);
            }
        }
    }
    __builtin_amdgcn_s_setprio(0);
    __syncthreads();   // Y1 dead

    f32x4 acc2[2][4] = {};
    #pragma unroll
    for (int kc = 0; kc < 2; ++kc) {
        // ---- [GEMM2(kc-1) ∥] epi1(kc): acc1[:,kc] -> X1[68][68] premult ----
        if (kc == 1) {
            __builtin_amdgcn_s_setprio(1);
            #pragma unroll
            for (int kt = 0; kt < 2; ++kt) {
                bf16x8 a[2][2];
                #pragma unroll
                for (int mt = 0; mt < 2; ++mt) {
                    int off = (wm*2 + mt) * 1024 + kt * 512 + lswz * 8;
                    a[mt][0] = *(const bf16x8*)(Y2h + off);
                    a[mt][1] = *(const bf16x8*)(Y2l + off);
                }
                #pragma unroll
                for (int nt = 0; nt < 4; ++nt) {
                    int woff = (nt*4 + wn) * 2048 + (0*2 + kt) * 512 + lane * 8;
                    bf16x8 wh = *(const bf16x8*)(wext + W2H + woff);
                    bf16x8 wl = *(const bf16x8*)(wext + W2L + woff);
                    #pragma unroll
                    for (int mt = 0; mt < 2; ++mt) {
                        MFMA3(acc2[mt][nt], a[mt][0], a[mt][1], wh, wl);
                    }
                }
            }
            __builtin_amdgcn_s_setprio(0);
        }
        // epi1(kc): wave's n-tile for this chunk (global tile kc*4+wn)
        #pragma unroll
        for (int mt = 0; mt < 3; ++mt) {
            int t = wm*3 + mt; if (t > 4) t = 4;
            int gcol = (kc*4 + wn)*16 + l15;
            int cl   = wn*16 + l15;
            float bv = b1[gcol];
            #pragma unroll
            for (int r = 0; r < 4; ++r) {
                int lr = t*16 + lg*4 + r;
                if (lr < 68)
                    X1[lr*68 + cl] =
                        dtab[lr + 9] * fmaxf(acc1[mt][kc][r] + bv, 0.f);
            }
        }
        __syncthreads();

        // ---- band2(kc): X1 -> Y2 [50 rows][64], zero pad 50..63 -----------
        {
            const int g = tid >> 4;                // 25 active groups x 2 rows
            const int c4 = (tid & 15) << 2;
            if (g < 25) {
                const int lr = g * 2;
                f32x4 ws = {};
                #pragma unroll
                for (int d = 0; d < 19; ++d)
                    ws += *(const f32x4*)(X1 + (lr + d) * 68 + c4);
                #pragma unroll
                for (int rr = 0; rr < 2; ++rr) {
                    if (rr) ws += *(const f32x4*)(X1 + (lr + rr + 18) * 68 + c4)
                                - *(const f32x4*)(X1 + (lr + rr - 1)  * 68 + c4);
                    int row = lr + rr;
                    if (row < 50) {
                        float dv = dtab[row + 18];
                        float y4[4] = {ws[0]*dv, ws[1]*dv, ws[2]*dv, ws[3]*dv};
                        int off = ywoff(row, c4, 1024);
                        pack_split4(y4, Y2h + off, Y2l + off);
                    }
                }
            }
            if (tid < 224) {                       // zero rows 50..63
                int off = ywoff(50 + (tid >> 4), (tid & 15) << 2, 1024);
                *(uint2*)(Y2h + off) = make_uint2(0, 0);
                *(uint2*)(Y2l + off) = make_uint2(0, 0);
            }
        }
        __syncthreads();
    }

    // ---- trailing GEMM2(kc=1) ----
    __builtin_amdgcn_s_setprio(1);
    #pragma unroll
    for (int kt = 0; kt < 2; ++kt) {
        bf16x8 a[2][2];
        #pragma unroll
        for (int mt = 0; mt < 2; ++mt) {
            int off = (wm*2 + mt) * 1024 + kt * 512 + lswz * 8;
            a[mt][0] = *(const bf16x8*)(Y2h + off);
            a[mt][1] = *(const bf16x8*)(Y2l + off);
        }
        #pragma unroll
        for (int nt = 0; nt < 4; ++nt) {
            int woff = (nt*4 + wn) * 2048 + (1*2 + kt) * 512 + lane * 8;
            bf16x8 wh = *(const bf16x8*)(wext + W2H + woff);
            bf16x8 wl = *(const bf16x8*)(wext + W2L + woff);
            #pragma unroll
            for (int mt = 0; mt < 2; ++mt) {
                MFMA3(acc2[mt][nt], a[mt][0], a[mt][1], wh, wl);
            }
        }
    }
    __builtin_amdgcn_s_setprio(0);
    __syncthreads();   // all Y2 reads done; X2 may overlay X1/Y2

    // ------- nc loop: epi2 -> X2 -> (band3 chunk -> Y3 -> GEMM3) x2 --------
    f32x4 acc3[2] = {};
    #pragma unroll
    for (int nc = 0; nc < 2; ++nc) {
        // epi2(nc): acc2 cols -> X2[50][132] premult
        #pragma unroll
        for (int mt = 0; mt < 2; ++mt)
        #pragma unroll
        for (int q = 0; q < 2; ++q) {
            int gcol = ((nc*2 + q)*4 + wn)*16 + l15;
            int cl   = (q*4 + wn)*16 + l15;
            float bv = b2[gcol];
            #pragma unroll
            for (int r = 0; r < 4; ++r) {
                int lr = (wm*2 + mt)*16 + lg*4 + r;
                if (lr < 50)
                    X2[lr*132 + cl] =
                        dtab[lr + 18] * fmaxf(acc2[mt][nc*2 + q][r] + bv, 0.f);
            }
        }
        __syncthreads();

        #pragma unroll
        for (int ncc = 0; ncc < 2; ++ncc) {
            {   // band3 chunk: X2 cols [ncc*64,+64) -> Y3 [32 rows][64]
                const int c4  = (tid & 15) << 2;   // 16 col groups
                const int row = tid >> 4;          // 1 row per thread (0..31)
                f32x4 ws = {};
                #pragma unroll
                for (int d = 0; d < 19; ++d)
                    ws += *(const f32x4*)(X2 + (row + d) * 132 + ncc*64 + c4);
                float dv = dtab[row + 27];
                float y4[4] = {ws[0]*dv, ws[1]*dv, ws[2]*dv, ws[3]*dv};
                int off = ywoff(row, c4, 1024);
                pack_split4(y4, Y3h + off, Y3l + off);
            }
            __syncthreads();

            // GEMM3 partial (k-chunk = 64)
            __builtin_amdgcn_s_setprio(1);
            #pragma unroll
            for (int kt = 0; kt < 2; ++kt) {
                int aoff = wm * 1024 + kt * 512 + lswz * 8;
                bf16x8 a0 = *(const bf16x8*)(Y3h + aoff);
                bf16x8 a1 = *(const bf16x8*)(Y3l + aoff);
                #pragma unroll
                for (int nt = 0; nt < 2; ++nt) {
                    int wkt = (nc*2 + ncc)*2 + kt;
                    int woff = (nt*4 + wn) * 4096 + wkt * 512 + lane * 8;
                    bf16x8 wh = *(const bf16x8*)(wext + W3H + woff);
                    bf16x8 wl = *(const bf16x8*)(wext + W3L + woff);
                    MFMA3(acc3[nt], a0, a1, wh, wl);
                }
            }
            __builtin_amdgcn_s_setprio(0);
            __syncthreads();   // Y3 reuse / X2 rewrite next iteration
        }
    }

    // ---------------- pool: column sums of relu(acc3 + b3) -----------------
    #pragma unroll
    for (int nt = 0; nt < 2; ++nt) {
        int g_t = nt*4 + wn;
        float bv = b3[g_t*16 + l15];
        float cs = 0.f;
        #pragma unroll
        for (int r = 0; r < 4; ++r) {
            int gr = r0 + wm*16 + lg*4 + r;
            if (gr < NN) cs += fmaxf(acc3[nt][r] + bv, 0.f);
        }
        cs += __shfl_xor(cs, 16);
        cs += __shfl_xor(cs, 32);
        if (lane < 16) atomicAdd(&pool[g_t*16 + lane], cs);
    }
    __syncthreads();
    if (tid < 128) partial[((size_t)b * 15 + rt) * 128 + tid] = pool[tid];
}

// ---------------------------------------------------------------------------
// wconv: W fp32 [K][N] -> bf16 hi/lo planes, fragment layout (unswizzled)
// ---------------------------------------------------------------------------
__global__ __launch_bounds__(256) void wconv(
    const float* __restrict__ W1, const float* __restrict__ W2,
    const float* __restrict__ W3, ushort_t* __restrict__ wext)
{
    int i = blockIdx.x * 256 + threadIdx.x;
    float w; int off_h, off_l, idx;
    if (i < 8192) {                       // W1: K=64,  N=128
        int k = i >> 7, n = i & 127;
        w = W1[i]; idx = frag_off(n, k, 1024);  off_h = W1H; off_l = W1L;
    } else if (i < 40960) {               // W2: K=128, N=256
        int j = i - 8192;
        int k = j >> 8, n = j & 255;
        w = W2[j]; idx = frag_off(n, k, 2048);  off_h = W2H; off_l = W2L;
    } else if (i < 73728) {               // W3: K=256, N=128
        int j = i - 40960;
        int k = j >> 7, n = j & 127;
        w = W3[j]; idx = frag_off(n, k, 4096);  off_h = W3H; off_l = W3L;
    } else return;
    __hip_bfloat16 hb = __float2bfloat16(w);
    float hf = __bfloat162float(hb);
    __hip_bfloat16 lb = __float2bfloat16(w - hf);
    wext[off_h + idx] = *(ushort_t*)&hb;
    wext[off_l + idx] = *(ushort_t*)&lb;
}

// ---------------------------------------------------------------------------
// head: gf = mean-pool reduce; features = relu(gf@Wf+bf); out = feats@Wc+bc
// ---------------------------------------------------------------------------
__global__ __launch_bounds__(512) void head_kernel(
    const float* __restrict__ partial, const float* __restrict__ Wf,
    const float* __restrict__ bf, const float* __restrict__ Wc,
    const float* __restrict__ bc, float* __restrict__ dout)
{
    __shared__ float gfs[128];
    __shared__ float feats[512];
    int b = blockIdx.x, t = threadIdx.x;
    if (t < 128) {
        const float* p = partial + (size_t)b * (15 * 128);
        float s = 0.f;
        #pragma unroll
        for (int tt = 0; tt < 15; ++tt) s += p[tt * 128 + t];
        s *= (1.0f / 468.0f);
        gfs[t] = s;
        dout[65792 + b * 128 + t] = s;       // graph_features
    }
    __syncthreads();
    float a = bf[t];
    for (int k = 0; k < 128; ++k) a += gfs[k] * Wf[k * 512 + t];
    a = fmaxf(a, 0.f);
    dout[256 + b * 512 + t] = a;             // features
    feats[t] = a;
    __syncthreads();
    if (t < 64) {
        float s0 = 0.f, s1 = 0.f;
        for (int c = t; c < 512; c += 64) {
            float f = feats[c];
            s0 += f * Wc[c * 2 + 0];
            s1 += f * Wc[c * 2 + 1];
        }
        #pragma unroll
        for (int off = 32; off; off >>= 1) {
            s0 += __shfl_down(s0, off);
            s1 += __shfl_down(s1, off);
        }
        if (t == 0) {
            dout[b * 2 + 0] = s0 + bc[0];
            dout[b * 2 + 1] = s1 + bc[1];
        }
    }
}

// ---------------------------------------------------------------------------
extern "C" void kernel_launch(void* const* d_in, const int* in_sizes, int n_in,
                              void* d_out, int out_size, void* d_ws, size_t ws_size,
                              hipStream_t stream)
{
    const float* landmarks = (const float*)d_in[0];
    const float* W_enc     = (const float*)d_in[1];
    const float* b_enc     = (const float*)d_in[2];
    const float* W1        = (const float*)d_in[3];
    const float* b1        = (const float*)d_in[4];
    const float* W2        = (const float*)d_in[5];
    const float* b2        = (const float*)d_in[6];
    const float* W3        = (const float*)d_in[7];
    const float* b3        = (const float*)d_in[8];
    const float* W_fus     = (const float*)d_in[9];
    const float* b_fus     = (const float*)d_in[10];
    const float* W_cls     = (const float*)d_in[11];
    const float* b_cls     = (const float*)d_in[12];
    float* out = (float*)d_out;

    char* ws = (char*)d_ws;
    ushort_t* wext = (ushort_t*)(ws + 0);        // 294,912 B
    float* partial = (float*)(ws + 294912);      // 983,040 B

    wconv<<<288, 256, 0, stream>>>(W1, W2, W3, wext);
    fused<<<dim3(15, 128), 512, 0, stream>>>(
        landmarks, wext, W_enc, b_enc, b1, b2, b3, partial);
    head_kernel<<<128, 512, 0, stream>>>(partial, W_fus, b_fus, W_cls, b_cls, out);
}

// Round 15
// 100.937 us; speedup vs baseline: 1.7902x; 1.7902x over previous
//
#include <hip/hip_runtime.h>
#include <hip/hip_bf16.h>

typedef __bf16 bf16x8 __attribute__((ext_vector_type(8)));
typedef float  f32x4  __attribute__((ext_vector_type(4)));
typedef unsigned short ushort_t;

#define NN 468

// wext element offsets (ushort), fragment-major planes (NOT swizzled)
#define W1H 0
#define W1L 8192
#define W2H 16384
#define W2L 49152
#define W3H 81920
#define W3L 114688

// LDS byte offsets — peak 35,736 B -> 4 blocks/CU possible
#define L_LM   0       // 258 f32 = 1032                   (phase A only)
#define L_Y1   8192    // 2 planes x 5120 ushort = 20480   [8192,28672) A..GEMM1
#define L_X1   0       // [68][68] f32 = 18496             [0,18496)  kc loop
#define L_Y2   18496   // 2 planes x 4096 ushort = 16384   [18496,34880) kc loop
#define L_X2   0       // [50][132] f32 = 26400            [0,26400)  nc loop
#define L_Y3   26400   // 2 planes x 2048 ushort = 8192    [26400,34592) k-chunked
#define L_DTAB 34880   // 86 f32 = 344
#define L_POOL 35224   // 128 f32 = 512  (ends 35736)

#define MFMA3(d, ah, al, wh, wl)                                        \
    d = __builtin_amdgcn_mfma_f32_16x16x32_bf16(ah, wh, d, 0, 0, 0);    \
    d = __builtin_amdgcn_mfma_f32_16x16x32_bf16(ah, wl, d, 0, 0, 0);    \
    d = __builtin_amdgcn_mfma_f32_16x16x32_bf16(al, wh, d, 0, 0, 0);

// ---------------------------------------------------------------------------
__device__ __forceinline__ void pack_split4(const float* y,
                                            ushort_t* hdst, ushort_t* ldst) {
    ushort_t h[4], l[4];
    #pragma unroll
    for (int j = 0; j < 4; ++j) {
        __hip_bfloat16 hb = __float2bfloat16(y[j]);
        float hf = __bfloat162float(hb);
        __hip_bfloat16 lb = __float2bfloat16(y[j] - hf);
        h[j] = *(ushort_t*)&hb; l[j] = *(ushort_t*)&lb;
    }
    uint2 hv = make_uint2((unsigned)h[0] | ((unsigned)h[1] << 16),
                          (unsigned)h[2] | ((unsigned)h[3] << 16));
    uint2 lv = make_uint2((unsigned)l[0] | ((unsigned)l[1] << 16),
                          (unsigned)l[2] | ((unsigned)l[3] << 16));
    *(uint2*)hdst = hv;
    *(uint2*)ldst = lv;
}

// unswizzled fragment offset (W planes in global memory)
__device__ __forceinline__ int frag_off(int r, int k, int K16) {
    return (r >> 4) * K16 + (k >> 5) * 512 + ((k >> 3) & 3) * 128
         + (r & 15) * 8 + (k & 7);
}

// swizzled Y-plane offset (LDS): unit' = q*16 + ((r ^ 2q) & 15)
__device__ __forceinline__ int ywoff(int r, int k4, int K16) {
    int q = (k4 >> 3) & 3;
    int u = q * 16 + (((r & 15) ^ (q << 1)) & 15);
    return (r >> 4) * K16 + (k4 >> 5) * 512 + u * 8 + (k4 & 7);
}

// ---------------------------------------------------------------------------
// fused: full 3-layer GCN chain for one (32-row tile, batch) in LDS.
// 512 threads = 8 waves (wm = w&1 over m, wn = w>>1 over n).
// Row frames: Y1/X1 lr1: gr = r0-18+lr1 (0..67)
//             Y2/X2 lr2: gr = r0-9+lr2  (0..49)
//             Y3     lr3: gr = r0+lr3   (0..31)
// Per-wave accumulators: acc1[3][2]=24, acc2[2][4]=32, acc3[2]=8 regs.
// launch_bounds(512,4): R12 compiled to VGPR=64 spill-free under this bound;
// with 35.8KB LDS the HW can then co-schedule 4 blocks/CU (32 waves).
// NOTE (R10/R13 lesson): NEVER raise min-waves to chase occupancy — it caps
// VGPRs and the allocator spills (R13: VGPR 32, 630MB scratch traffic).
// ---------------------------------------------------------------------------
__global__ __launch_bounds__(512, 4) void fused(
    const float* __restrict__ Lm, const ushort_t* __restrict__ wext,
    const float* __restrict__ We, const float* __restrict__ be,
    const float* __restrict__ b1, const float* __restrict__ b2,
    const float* __restrict__ b3, float* __restrict__ partial)
{
    __shared__ __align__(16) char lds[35840];
    float*    lmst = (float*)(lds + L_LM);
    ushort_t* Y1h  = (ushort_t*)(lds + L_Y1);  ushort_t* Y1l = Y1h + 5120;
    float*    X1   = (float*)(lds + L_X1);
    ushort_t* Y2h  = (ushort_t*)(lds + L_Y2);  ushort_t* Y2l = Y2h + 4096;
    float*    X2   = (float*)(lds + L_X2);
    ushort_t* Y3h  = (ushort_t*)(lds + L_Y3);  ushort_t* Y3l = Y3h + 2048;
    float*    dtab = (float*)(lds + L_DTAB);
    float*    pool = (float*)(lds + L_POOL);

    const int tid  = threadIdx.x;
    const int lane = tid & 63;
    const int wave = tid >> 6;            // 0..7
    const int wm = wave & 1, wn = wave >> 1;   // wn in 0..3
    const int l15 = lane & 15, lg = lane >> 4;
    const int lswz = (lane & 48) + (((lane & 15) ^ ((lane >> 4) << 1)) & 15);
    const int rt = blockIdx.x, b = blockIdx.y;
    const int r0 = rt * 32;

    // ---------------- stage: dinv table, landmarks, pool init -------------
    if (tid < 86) {
        int ri = r0 - 27 + tid;
        float dv = 0.f;
        if (ri >= 0 && ri < NN) {
            int lo = ri - 9; if (lo < 0) lo = 0;
            int hi = ri + 9; if (hi > NN - 1) hi = NN - 1;
            dv = 1.0f / sqrtf((float)(hi - lo + 1));
        }
        dtab[tid] = dv;
    }
    if (tid < 258) {
        int g = (r0 - 27) * 3 + tid;
        lmst[tid] = (g >= 0 && g < NN * 3) ? Lm[(size_t)b * (NN * 3) + g] : 0.f;
    }
    if (tid < 128) pool[tid] = 0.f;
    __syncthreads();

    // ---------------- band1 (in-register, encoder fused) -> Y1 -------------
    {
        const int c = tid & 63, s = tid >> 6;      // 8 slices x 9 rows
        const float w0 = We[c], w1 = We[64 + c], w2 = We[128 + c], bk = be[c];
        float z[27];
        #pragma unroll
        for (int j = 0; j < 27; ++j) {
            int li = s * 9 + j;                    // local row in 86-frame
            float v = 0.f;
            if (li < 86) {
                float x = bk + lmst[li*3]*w0 + lmst[li*3+1]*w1 + lmst[li*3+2]*w2;
                v = x * dtab[li];                  // dtab=0 masks OOR rows
            }
            z[j] = v;
        }
        float ws = 0.f;
        #pragma unroll
        for (int j = 0; j < 19; ++j) ws += z[j];
        #pragma unroll
        for (int rr = 0; rr < 9; ++rr) {
            if (rr) ws += z[rr + 18] - z[rr - 1];
            int lr = s * 9 + rr;
            if (lr < 68) {
                float y = ws * dtab[lr + 9];
                __hip_bfloat16 hb = __float2bfloat16(y);
                float hf = __bfloat162float(hb);
                __hip_bfloat16 lb = __float2bfloat16(y - hf);
                int off = ywoff(lr, c, 1024);
                Y1h[off] = *(ushort_t*)&hb;
                Y1l[off] = *(ushort_t*)&lb;
            }
        }
        for (int e = tid; e < 192; e += 512) {     // zero pad rows 68..79
            int off = ywoff(68 + (e >> 4), (e & 15) << 2, 1024);
            *(uint2*)(Y1h + off) = make_uint2(0, 0);
            *(uint2*)(Y1l + off) = make_uint2(0, 0);
        }
    }
    __syncthreads();

    // ---------------- GEMM1: Y1(5 tiles) @ W1 ------------------------------
    // m: wm*3+mt clamped to 4 (tile 4 duplicated, benign); n: ntile = nt*4+wn
    f32x4 acc1[3][2] = {};
    __builtin_amdgcn_s_setprio(1);
    #pragma unroll
    for (int kt = 0; kt < 2; ++kt) {
        bf16x8 a[3][2];
        #pragma unroll
        for (int mt = 0; mt < 3; ++mt) {
            int t = wm*3 + mt; if (t > 4) t = 4;
            int off = t * 1024 + kt * 512 + lswz * 8;
            a[mt][0] = *(const bf16x8*)(Y1h + off);
            a[mt][1] = *(const bf16x8*)(Y1l + off);
        }
        #pragma unroll
        for (int nt = 0; nt < 2; ++nt) {
            int woff = (nt*4 + wn) * 1024 + kt * 512 + lane * 8;
            bf16x8 wh = *(const bf16x8*)(wext + W1H + woff);
            bf16x8 wl = *(const bf16x8*)(wext + W1L + woff);
            #pragma unroll
            for (int mt = 0; mt < 3; ++mt) {
                MFMA3(acc1[mt][nt], a[mt][0], a[mt][1], wh, wl);
            }
        }
    }
    __builtin_amdgcn_s_setprio(0);
    __syncthreads();   // Y1 dead

    f32x4 acc2[2][4] = {};
    #pragma unroll
    for (int kc = 0; kc < 2; ++kc) {
        // ---- [GEMM2(kc-1) ∥] epi1(kc): acc1[:,kc] -> X1[68][68] premult ----
        if (kc == 1) {
            __builtin_amdgcn_s_setprio(1);
            #pragma unroll
            for (int kt = 0; kt < 2; ++kt) {
                bf16x8 a[2][2];
                #pragma unroll
                for (int mt = 0; mt < 2; ++mt) {
                    int off = (wm*2 + mt) * 1024 + kt * 512 + lswz * 8;
                    a[mt][0] = *(const bf16x8*)(Y2h + off);
                    a[mt][1] = *(const bf16x8*)(Y2l + off);
                }
                #pragma unroll
                for (int nt = 0; nt < 4; ++nt) {
                    int woff = (nt*4 + wn) * 2048 + (0*2 + kt) * 512 + lane * 8;
                    bf16x8 wh = *(const bf16x8*)(wext + W2H + woff);
                    bf16x8 wl = *(const bf16x8*)(wext + W2L + woff);
                    #pragma unroll
                    for (int mt = 0; mt < 2; ++mt) {
                        MFMA3(acc2[mt][nt], a[mt][0], a[mt][1], wh, wl);
                    }
                }
            }
            __builtin_amdgcn_s_setprio(0);
        }
        // epi1(kc): wave's n-tile for this chunk (global tile kc*4+wn)
        #pragma unroll
        for (int mt = 0; mt < 3; ++mt) {
            int t = wm*3 + mt; if (t > 4) t = 4;
            int gcol = (kc*4 + wn)*16 + l15;
            int cl   = wn*16 + l15;
            float bv = b1[gcol];
            #pragma unroll
            for (int r = 0; r < 4; ++r) {
                int lr = t*16 + lg*4 + r;
                if (lr < 68)
                    X1[lr*68 + cl] =
                        dtab[lr + 9] * fmaxf(acc1[mt][kc][r] + bv, 0.f);
            }
        }
        __syncthreads();

        // ---- band2(kc): X1 -> Y2 [50 rows][64], zero pad 50..63 -----------
        {
            const int g = tid >> 4;                // 25 active groups x 2 rows
            const int c4 = (tid & 15) << 2;
            if (g < 25) {
                const int lr = g * 2;
                f32x4 ws = {};
                #pragma unroll
                for (int d = 0; d < 19; ++d)
                    ws += *(const f32x4*)(X1 + (lr + d) * 68 + c4);
                #pragma unroll
                for (int rr = 0; rr < 2; ++rr) {
                    if (rr) ws += *(const f32x4*)(X1 + (lr + rr + 18) * 68 + c4)
                                - *(const f32x4*)(X1 + (lr + rr - 1)  * 68 + c4);
                    int row = lr + rr;
                    if (row < 50) {
                        float dv = dtab[row + 18];
                        float y4[4] = {ws[0]*dv, ws[1]*dv, ws[2]*dv, ws[3]*dv};
                        int off = ywoff(row, c4, 1024);
                        pack_split4(y4, Y2h + off, Y2l + off);
                    }
                }
            }
            if (tid < 224) {                       // zero rows 50..63
                int off = ywoff(50 + (tid >> 4), (tid & 15) << 2, 1024);
                *(uint2*)(Y2h + off) = make_uint2(0, 0);
                *(uint2*)(Y2l + off) = make_uint2(0, 0);
            }
        }
        __syncthreads();
    }

    // ---- trailing GEMM2(kc=1) ----
    __builtin_amdgcn_s_setprio(1);
    #pragma unroll
    for (int kt = 0; kt < 2; ++kt) {
        bf16x8 a[2][2];
        #pragma unroll
        for (int mt = 0; mt < 2; ++mt) {
            int off = (wm*2 + mt) * 1024 + kt * 512 + lswz * 8;
            a[mt][0] = *(const bf16x8*)(Y2h + off);
            a[mt][1] = *(const bf16x8*)(Y2l + off);
        }
        #pragma unroll
        for (int nt = 0; nt < 4; ++nt) {
            int woff = (nt*4 + wn) * 2048 + (1*2 + kt) * 512 + lane * 8;
            bf16x8 wh = *(const bf16x8*)(wext + W2H + woff);
            bf16x8 wl = *(const bf16x8*)(wext + W2L + woff);
            #pragma unroll
            for (int mt = 0; mt < 2; ++mt) {
                MFMA3(acc2[mt][nt], a[mt][0], a[mt][1], wh, wl);
            }
        }
    }
    __builtin_amdgcn_s_setprio(0);
    __syncthreads();   // all Y2 reads done; X2 may overlay X1/Y2

    // ------- nc loop: epi2 -> X2 -> (band3 chunk -> Y3 -> GEMM3) x2 --------
    f32x4 acc3[2] = {};
    #pragma unroll
    for (int nc = 0; nc < 2; ++nc) {
        // epi2(nc): acc2 cols -> X2[50][132] premult
        #pragma unroll
        for (int mt = 0; mt < 2; ++mt)
        #pragma unroll
        for (int q = 0; q < 2; ++q) {
            int gcol = ((nc*2 + q)*4 + wn)*16 + l15;
            int cl   = (q*4 + wn)*16 + l15;
            float bv = b2[gcol];
            #pragma unroll
            for (int r = 0; r < 4; ++r) {
                int lr = (wm*2 + mt)*16 + lg*4 + r;
                if (lr < 50)
                    X2[lr*132 + cl] =
                        dtab[lr + 18] * fmaxf(acc2[mt][nc*2 + q][r] + bv, 0.f);
            }
        }
        __syncthreads();

        #pragma unroll
        for (int ncc = 0; ncc < 2; ++ncc) {
            {   // band3 chunk: X2 cols [ncc*64,+64) -> Y3 [32 rows][64]
                const int c4  = (tid & 15) << 2;   // 16 col groups
                const int row = tid >> 4;          // 1 row per thread (0..31)
                f32x4 ws = {};
                #pragma unroll
                for (int d = 0; d < 19; ++d)
                    ws += *(const f32x4*)(X2 + (row + d) * 132 + ncc*64 + c4);
                float dv = dtab[row + 27];
                float y4[4] = {ws[0]*dv, ws[1]*dv, ws[2]*dv, ws[3]*dv};
                int off = ywoff(row, c4, 1024);
                pack_split4(y4, Y3h + off, Y3l + off);
            }
            __syncthreads();

            // GEMM3 partial (k-chunk = 64)
            __builtin_amdgcn_s_setprio(1);
            #pragma unroll
            for (int kt = 0; kt < 2; ++kt) {
                int aoff = wm * 1024 + kt * 512 + lswz * 8;
                bf16x8 a0 = *(const bf16x8*)(Y3h + aoff);
                bf16x8 a1 = *(const bf16x8*)(Y3l + aoff);
                #pragma unroll
                for (int nt = 0; nt < 2; ++nt) {
                    int wkt = (nc*2 + ncc)*2 + kt;
                    int woff = (nt*4 + wn) * 4096 + wkt * 512 + lane * 8;
                    bf16x8 wh = *(const bf16x8*)(wext + W3H + woff);
                    bf16x8 wl = *(const bf16x8*)(wext + W3L + woff);
                    MFMA3(acc3[nt], a0, a1, wh, wl);
                }
            }
            __builtin_amdgcn_s_setprio(0);
            __syncthreads();   // Y3 reuse / X2 rewrite next iteration
        }
    }

    // ---------------- pool: column sums of relu(acc3 + b3) -----------------
    #pragma unroll
    for (int nt = 0; nt < 2; ++nt) {
        int g_t = nt*4 + wn;
        float bv = b3[g_t*16 + l15];
        float cs = 0.f;
        #pragma unroll
        for (int r = 0; r < 4; ++r) {
            int gr = r0 + wm*16 + lg*4 + r;
            if (gr < NN) cs += fmaxf(acc3[nt][r] + bv, 0.f);
        }
        cs += __shfl_xor(cs, 16);
        cs += __shfl_xor(cs, 32);
        if (lane < 16) atomicAdd(&pool[g_t*16 + lane], cs);
    }
    __syncthreads();
    if (tid < 128) partial[((size_t)b * 15 + rt) * 128 + tid] = pool[tid];
}

// ---------------------------------------------------------------------------
// wconv: W fp32 [K][N] -> bf16 hi/lo planes, fragment layout (unswizzled)
// ---------------------------------------------------------------------------
__global__ __launch_bounds__(256) void wconv(
    const float* __restrict__ W1, const float* __restrict__ W2,
    const float* __restrict__ W3, ushort_t* __restrict__ wext)
{
    int i = blockIdx.x * 256 + threadIdx.x;
    float w; int off_h, off_l, idx;
    if (i < 8192) {                       // W1: K=64,  N=128
        int k = i >> 7, n = i & 127;
        w = W1[i]; idx = frag_off(n, k, 1024);  off_h = W1H; off_l = W1L;
    } else if (i < 40960) {               // W2: K=128, N=256
        int j = i - 8192;
        int k = j >> 8, n = j & 255;
        w = W2[j]; idx = frag_off(n, k, 2048);  off_h = W2H; off_l = W2L;
    } else if (i < 73728) {               // W3: K=256, N=128
        int j = i - 40960;
        int k = j >> 7, n = j & 127;
        w = W3[j]; idx = frag_off(n, k, 4096);  off_h = W3H; off_l = W3L;
    } else return;
    __hip_bfloat16 hb = __float2bfloat16(w);
    float hf = __bfloat162float(hb);
    __hip_bfloat16 lb = __float2bfloat16(w - hf);
    wext[off_h + idx] = *(ushort_t*)&hb;
    wext[off_l + idx] = *(ushort_t*)&lb;
}

// ---------------------------------------------------------------------------
// head: gf = mean-pool reduce; features = relu(gf@Wf+bf); out = feats@Wc+bc
// ---------------------------------------------------------------------------
__global__ __launch_bounds__(512) void head_kernel(
    const float* __restrict__ partial, const float* __restrict__ Wf,
    const float* __restrict__ bf, const float* __restrict__ Wc,
    const float* __restrict__ bc, float* __restrict__ dout)
{
    __shared__ float gfs[128];
    __shared__ float feats[512];
    int b = blockIdx.x, t = threadIdx.x;
    if (t < 128) {
        const float* p = partial + (size_t)b * (15 * 128);
        float s = 0.f;
        #pragma unroll
        for (int tt = 0; tt < 15; ++tt) s += p[tt * 128 + t];
        s *= (1.0f / 468.0f);
        gfs[t] = s;
        dout[65792 + b * 128 + t] = s;       // graph_features
    }
    __syncthreads();
    float a = bf[t];
    for (int k = 0; k < 128; ++k) a += gfs[k] * Wf[k * 512 + t];
    a = fmaxf(a, 0.f);
    dout[256 + b * 512 + t] = a;             // features
    feats[t] = a;
    __syncthreads();
    if (t < 64) {
        float s0 = 0.f, s1 = 0.f;
        for (int c = t; c < 512; c += 64) {
            float f = feats[c];
            s0 += f * Wc[c * 2 + 0];
            s1 += f * Wc[c * 2 + 1];
        }
        #pragma unroll
        for (int off = 32; off; off >>= 1) {
            s0 += __shfl_down(s0, off);
            s1 += __shfl_down(s1, off);
        }
        if (t == 0) {
            dout[b * 2 + 0] = s0 + bc[0];
            dout[b * 2 + 1] = s1 + bc[1];
        }
    }
}

// ---------------------------------------------------------------------------
extern "C" void kernel_launch(void* const* d_in, const int* in_sizes, int n_in,
                              void* d_out, int out_size, void* d_ws, size_t ws_size,
                              hipStream_t stream)
{
    const float* landmarks = (const float*)d_in[0];
    const float* W_enc     = (const float*)d_in[1];
    const float* b_enc     = (const float*)d_in[2];
    const float* W1        = (const float*)d_in[3];
    const float* b1        = (const float*)d_in[4];
    const float* W2        = (const float*)d_in[5];
    const float* b2        = (const float*)d_in[6];
    const float* W3        = (const float*)d_in[7];
    const float* b3        = (const float*)d_in[8];
    const float* W_fus     = (const float*)d_in[9];
    const float* b_fus     = (const float*)d_in[10];
    const float* W_cls     = (const float*)d_in[11];
    const float* b_cls     = (const float*)d_in[12];
    float* out = (float*)d_out;

    char* ws = (char*)d_ws;
    ushort_t* wext = (ushort_t*)(ws + 0);        // 294,912 B
    float* partial = (float*)(ws + 294912);      // 983,040 B

    wconv<<<288, 256, 0, stream>>>(W1, W2, W3, wext);
    fused<<<dim3(15, 128), 512, 0, stream>>>(
        landmarks, wext, W_enc, b_enc, b1, b2, b3, partial);
    head_kernel<<<128, 512, 0, stream>>>(partial, W_fus, b_fus, W_cls, b_cls, out);
}

// Round 16
// 69.590 us; speedup vs baseline: 2.5966x; 1.4505x over previous
//
#include <hip/hip_runtime.h>
#include <hip/hip_bf16.h>

typedef __bf16 bf16x8 __attribute__((ext_vector_type(8)));
typedef float  f32x4  __attribute__((ext_vector_type(4)));
typedef unsigned short ushort_t;

#define NN 468

// wext element offsets (ushort), fragment-major planes (NOT swizzled)
#define W1H 0
#define W1L 8192
#define W2H 16384
#define W2L 49152
#define W3H 81920
#define W3L 114688

// ---- LDS layout (64-row tile, peak 77,056 B -> 2 blocks/CU) ----
// region0 [0, 43296): X0[118][68]f32 (32096) -> X1h[100][68]f32 (27200)
//                     -> X2c[82][132]f32 (43296)
// region1 [43296, 76064): lmst(1416) / Y1 2x7168us (28672)
//                     -> Y2h 2x6144us (24576) -> Y3 2x8192us (32768)
#define L_X0   0
#define L_X1   0
#define L_X2   0
#define R1     43296
#define L_DTAB 76064   // 118 f32 = 472
#define L_POOL 76544   // 128 f32 = 512 (ends 77056)

#define MFMA3(d, ah, al, wh, wl)                                        \
    d = __builtin_amdgcn_mfma_f32_16x16x32_bf16(ah, wh, d, 0, 0, 0);    \
    d = __builtin_amdgcn_mfma_f32_16x16x32_bf16(ah, wl, d, 0, 0, 0);    \
    d = __builtin_amdgcn_mfma_f32_16x16x32_bf16(al, wh, d, 0, 0, 0);

// ---------------------------------------------------------------------------
__device__ __forceinline__ void pack_split4(const float* y,
                                            ushort_t* hdst, ushort_t* ldst) {
    ushort_t h[4], l[4];
    #pragma unroll
    for (int j = 0; j < 4; ++j) {
        __hip_bfloat16 hb = __float2bfloat16(y[j]);
        float hf = __bfloat162float(hb);
        __hip_bfloat16 lb = __float2bfloat16(y[j] - hf);
        h[j] = *(ushort_t*)&hb; l[j] = *(ushort_t*)&lb;
    }
    uint2 hv = make_uint2((unsigned)h[0] | ((unsigned)h[1] << 16),
                          (unsigned)h[2] | ((unsigned)h[3] << 16));
    uint2 lv = make_uint2((unsigned)l[0] | ((unsigned)l[1] << 16),
                          (unsigned)l[2] | ((unsigned)l[3] << 16));
    *(uint2*)hdst = hv;
    *(uint2*)ldst = lv;
}

// unswizzled fragment offset (W planes in global memory)
__device__ __forceinline__ int frag_off(int r, int k, int K16) {
    return (r >> 4) * K16 + (k >> 5) * 512 + ((k >> 3) & 3) * 128
         + (r & 15) * 8 + (k & 7);
}

// swizzled Y-plane offset (LDS): unit' = q*16 + ((r ^ 2q) & 15)
__device__ __forceinline__ int ywoff(int r, int k4, int K16) {
    int q = (k4 >> 3) & 3;
    int u = q * 16 + (((r & 15) ^ (q << 1)) & 15);
    return (r >> 4) * K16 + (k4 >> 5) * 512 + u * 8 + (k4 & 7);
}

// ---------------------------------------------------------------------------
// fused: full 3-layer GCN chain for one (64-row tile, batch) in LDS.
// 512 threads = 8 waves (wm = w&1 over m, wn = w>>1 over n).
// Frames (dtab[t] = dinv(r0-27+t), t<118):
//   X0 row l0 : gr = r0-27+l0  (0..117)
//   Y1/X1 lr1 : gr = r0-18+lr1 (0..99, Y1 padded to 112 = 7 tiles)
//   Y2/X2 lr2 : gr = r0-9+lr2  (0..81, Y2 padded to 96 = 6 tiles)
//   Y3    lr3 : gr = r0+lr3    (0..63, 4 tiles)
// Per-wave acc: acc1[4][2]=32, acc2[3][4]=48, acc3[2][2]=16.
// launch_bounds(512,4): cap 128 regs — NEVER raise min-waves (R10/R13: spill).
// ---------------------------------------------------------------------------
__global__ __launch_bounds__(512, 4) void fused(
    const float* __restrict__ Lm, const ushort_t* __restrict__ wext,
    const float* __restrict__ We, const float* __restrict__ be,
    const float* __restrict__ b1, const float* __restrict__ b2,
    const float* __restrict__ b3, float* __restrict__ partial)
{
    __shared__ __align__(16) char lds[77056];
    float*    X0   = (float*)(lds + L_X0);
    float*    X1   = (float*)(lds + L_X1);
    float*    X2   = (float*)(lds + L_X2);
    float*    lmst = (float*)(lds + R1);
    ushort_t* Y1h  = (ushort_t*)(lds + R1);  ushort_t* Y1l = Y1h + 7168;
    ushort_t* Y2h  = (ushort_t*)(lds + R1);  ushort_t* Y2l = Y2h + 6144;
    ushort_t* Y3h  = (ushort_t*)(lds + R1);  ushort_t* Y3l = Y3h + 8192;
    float*    dtab = (float*)(lds + L_DTAB);
    float*    pool = (float*)(lds + L_POOL);

    const int tid  = threadIdx.x;
    const int lane = tid & 63;
    const int wave = tid >> 6;                 // 0..7
    const int wm = wave & 1, wn = wave >> 1;   // wn in 0..3
    const int l15 = lane & 15, lg = lane >> 4;
    const int lswz = (lane & 48) + (((lane & 15) ^ ((lane >> 4) << 1)) & 15);
    const int rt = blockIdx.x, b = blockIdx.y;
    const int r0 = rt * 64;

    // ---------------- stage: dinv table, landmarks, pool init -------------
    if (tid < 118) {
        int ri = r0 - 27 + tid;
        float dv = 0.f;
        if (ri >= 0 && ri < NN) {
            int lo = ri - 9; if (lo < 0) lo = 0;
            int hi = ri + 9; if (hi > NN - 1) hi = NN - 1;
            dv = 1.0f / sqrtf((float)(hi - lo + 1));
        }
        dtab[tid] = dv;
    }
    if (tid < 354) {
        int g = (r0 - 27) * 3 + tid;
        lmst[tid] = (g >= 0 && g < NN * 3) ? Lm[(size_t)b * (NN * 3) + g] : 0.f;
    }
    if (tid < 128) pool[tid] = 0.f;
    __syncthreads();

    // ---------------- enc: X0[118][68] = enc(row) * dinv -------------------
    {
        const int c = tid & 63;
        const float w0 = We[c], w1 = We[64 + c], w2 = We[128 + c], bk = be[c];
        for (int l0 = tid >> 6; l0 < 118; l0 += 8) {
            float x = bk + lmst[l0*3]*w0 + lmst[l0*3+1]*w1 + lmst[l0*3+2]*w2;
            X0[l0 * 68 + c] = x * dtab[l0];
        }
    }
    __syncthreads();    // X0 ready; lmst dead (Y1 may overwrite)

    // ---------------- band1: X0 -> Y1 [100 rows][64], pad to 112 -----------
    {
        const int c4 = (tid & 15) << 2;
        const int base = (tid >> 4) * 4;       // 32 groups x 4 rows = 128>=112
        if (base < 100) {
            f32x4 ws = {};
            #pragma unroll
            for (int d = 0; d < 19; ++d)
                ws += *(const f32x4*)(X0 + (base + d) * 68 + c4);
            #pragma unroll
            for (int rr = 0; rr < 4; ++rr) {
                int row = base + rr;
                if (rr) ws += *(const f32x4*)(X0 + (row + 18) * 68 + c4)
                            - *(const f32x4*)(X0 + (row - 1)  * 68 + c4);
                float dv = dtab[row + 9];
                float y4[4] = {ws[0]*dv, ws[1]*dv, ws[2]*dv, ws[3]*dv};
                int off = ywoff(row, c4, 1024);
                pack_split4(y4, Y1h + off, Y1l + off);
            }
        } else if (base < 112) {               // zero pad rows 100..111
            float z4[4] = {0.f, 0.f, 0.f, 0.f};
            #pragma unroll
            for (int rr = 0; rr < 4; ++rr) {
                int row = base + rr;
                if (row < 112) {
                    int off = ywoff(row, c4, 1024);
                    pack_split4(z4, Y1h + off, Y1l + off);
                }
            }
        }
    }
    __syncthreads();

    // ---------------- GEMM1: Y1(7 tiles) @ W1 ------------------------------
    // m: t = wm*4+mt clamp 6 (tile 6 duplicated, benign); n: ntile = nt*4+wn
    f32x4 acc1[4][2] = {};
    __builtin_amdgcn_s_setprio(1);
    #pragma unroll
    for (int kt = 0; kt < 2; ++kt) {
        bf16x8 a[4][2];
        #pragma unroll
        for (int mt = 0; mt < 4; ++mt) {
            int t = wm*4 + mt; if (t > 6) t = 6;
            int off = t * 1024 + kt * 512 + lswz * 8;
            a[mt][0] = *(const bf16x8*)(Y1h + off);
            a[mt][1] = *(const bf16x8*)(Y1l + off);
        }
        #pragma unroll
        for (int nt = 0; nt < 2; ++nt) {
            int woff = (nt*4 + wn) * 1024 + kt * 512 + lane * 8;
            bf16x8 wh = *(const bf16x8*)(wext + W1H + woff);
            bf16x8 wl = *(const bf16x8*)(wext + W1L + woff);
            #pragma unroll
            for (int mt = 0; mt < 4; ++mt) {
                MFMA3(acc1[mt][nt], a[mt][0], a[mt][1], wh, wl);
            }
        }
    }
    __builtin_amdgcn_s_setprio(0);
    // no barrier: epi1 writes X1h (region0); X0 readers barrier'd already,
    // X1h does not overlap Y1 (region1).

    f32x4 acc2[3][4] = {};
    #pragma unroll
    for (int kc = 0; kc < 2; ++kc) {
        // ---- [GEMM2(kc-1) ∥] epi1(kc) ----
        if (kc == 1) {
            __builtin_amdgcn_s_setprio(1);
            #pragma unroll
            for (int kt = 0; kt < 2; ++kt) {
                bf16x8 a[3][2];
                #pragma unroll
                for (int mt = 0; mt < 3; ++mt) {
                    int off = (wm*3 + mt) * 1024 + kt * 512 + lswz * 8;
                    a[mt][0] = *(const bf16x8*)(Y2h + off);
                    a[mt][1] = *(const bf16x8*)(Y2l + off);
                }
                #pragma unroll
                for (int nt = 0; nt < 4; ++nt) {
                    int woff = (nt*4 + wn) * 2048 + (0*2 + kt) * 512 + lane * 8;
                    bf16x8 wh = *(const bf16x8*)(wext + W2H + woff);
                    bf16x8 wl = *(const bf16x8*)(wext + W2L + woff);
                    #pragma unroll
                    for (int mt = 0; mt < 3; ++mt) {
                        MFMA3(acc2[mt][nt], a[mt][0], a[mt][1], wh, wl);
                    }
                }
            }
            __builtin_amdgcn_s_setprio(0);
        }
        // epi1(kc): acc1[:,kc] -> X1h[100][68] premult
        #pragma unroll
        for (int mt = 0; mt < 4; ++mt) {
            int t = wm*4 + mt; if (t > 6) t = 6;
            int gcol = (kc*4 + wn)*16 + l15;
            int cl   = wn*16 + l15;
            float bv = b1[gcol];
            #pragma unroll
            for (int r = 0; r < 4; ++r) {
                int lr1 = t*16 + lg*4 + r;
                if (lr1 < 100)
                    X1[lr1*68 + cl] =
                        dtab[lr1 + 9] * fmaxf(acc1[mt][kc][r] + bv, 0.f);
            }
        }
        __syncthreads();

        // ---- band2(kc): X1h -> Y2 [82 rows][64], pad to 96 ----------------
        {
            const int c4   = (tid & 15) << 2;
            const int base = (tid >> 4) * 3;   // 32 groups x 3 rows = 96
            f32x4 ws = {};
            if (base < 82) {
                #pragma unroll
                for (int d = 0; d < 19; ++d)
                    ws += *(const f32x4*)(X1 + (base + d) * 68 + c4);
            }
            #pragma unroll
            for (int rr = 0; rr < 3; ++rr) {
                int row = base + rr;
                if (row < 96) {
                    float y4[4] = {0.f, 0.f, 0.f, 0.f};
                    if (row < 82) {
                        if (rr) ws += *(const f32x4*)(X1 + (row + 18) * 68 + c4)
                                    - *(const f32x4*)(X1 + (row - 1)  * 68 + c4);
                        float dv = dtab[row + 18];
                        y4[0] = ws[0]*dv; y4[1] = ws[1]*dv;
                        y4[2] = ws[2]*dv; y4[3] = ws[3]*dv;
                    }
                    int off = ywoff(row, c4, 1024);
                    pack_split4(y4, Y2h + off, Y2l + off);
                }
            }
        }
        __syncthreads();
    }

    // ---- trailing GEMM2(kc=1) ----
    __builtin_amdgcn_s_setprio(1);
    #pragma unroll
    for (int kt = 0; kt < 2; ++kt) {
        bf16x8 a[3][2];
        #pragma unroll
        for (int mt = 0; mt < 3; ++mt) {
            int off = (wm*3 + mt) * 1024 + kt * 512 + lswz * 8;
            a[mt][0] = *(const bf16x8*)(Y2h + off);
            a[mt][1] = *(const bf16x8*)(Y2l + off);
        }
        #pragma unroll
        for (int nt = 0; nt < 4; ++nt) {
            int woff = (nt*4 + wn) * 2048 + (1*2 + kt) * 512 + lane * 8;
            bf16x8 wh = *(const bf16x8*)(wext + W2H + woff);
            bf16x8 wl = *(const bf16x8*)(wext + W2L + woff);
            #pragma unroll
            for (int mt = 0; mt < 3; ++mt) {
                MFMA3(acc2[mt][nt], a[mt][0], a[mt][1], wh, wl);
            }
        }
    }
    __builtin_amdgcn_s_setprio(0);
    // epi2(0) writes X2c over X1h: X1h last read at band2(1)'s barrier ✓

    // ------- nc loop: [GEMM3(nc-1) ∥] epi2 -> X2c -> band3 -> Y3 -> GEMM3 --
    f32x4 acc3[2][2] = {};
    #pragma unroll
    for (int nc = 0; nc < 2; ++nc) {
        if (nc == 1) {
            __builtin_amdgcn_s_setprio(1);
            #pragma unroll
            for (int kt = 0; kt < 4; ++kt) {
                bf16x8 a0[2], a1[2];
                #pragma unroll
                for (int mt = 0; mt < 2; ++mt) {
                    int aoff = (wm*2 + mt) * 2048 + kt * 512 + lswz * 8;
                    a0[mt] = *(const bf16x8*)(Y3h + aoff);
                    a1[mt] = *(const bf16x8*)(Y3l + aoff);
                }
                #pragma unroll
                for (int nt = 0; nt < 2; ++nt) {
                    int woff = (nt*4 + wn) * 4096 + (0*4 + kt) * 512 + lane * 8;
                    bf16x8 wh = *(const bf16x8*)(wext + W3H + woff);
                    bf16x8 wl = *(const bf16x8*)(wext + W3L + woff);
                    #pragma unroll
                    for (int mt = 0; mt < 2; ++mt) {
                        MFMA3(acc3[mt][nt], a0[mt], a1[mt], wh, wl);
                    }
                }
            }
            __builtin_amdgcn_s_setprio(0);
        }
        // epi2(nc): acc2 n-chunk -> X2c[82][132] premult
        #pragma unroll
        for (int mt = 0; mt < 3; ++mt)
        #pragma unroll
        for (int q = 0; q < 2; ++q) {
            int gcol = ((nc*2 + q)*4 + wn)*16 + l15;
            int cl   = (q*4 + wn)*16 + l15;
            float bv = b2[gcol];
            #pragma unroll
            for (int r = 0; r < 4; ++r) {
                int lr2 = (wm*3 + mt)*16 + lg*4 + r;
                if (lr2 < 82)
                    X2[lr2*132 + cl] =
                        dtab[lr2 + 18] * fmaxf(acc2[mt][nc*2 + q][r] + bv, 0.f);
            }
        }
        __syncthreads();

        // ---- band3(nc): X2c -> Y3 [64 rows][128] --------------------------
        {
            const int c4   = (tid & 31) << 2;  // 128 cols
            const int base = (tid >> 5) * 4;   // 16 groups x 4 rows = 64
            f32x4 ws = {};
            #pragma unroll
            for (int d = 0; d < 19; ++d)
                ws += *(const f32x4*)(X2 + (base + d) * 132 + c4);
            #pragma unroll
            for (int rr = 0; rr < 4; ++rr) {
                int row = base + rr;
                if (rr) ws += *(const f32x4*)(X2 + (row + 18) * 132 + c4)
                            - *(const f32x4*)(X2 + (row - 1)  * 132 + c4);
                float dv = dtab[row + 27];
                float y4[4] = {ws[0]*dv, ws[1]*dv, ws[2]*dv, ws[3]*dv};
                int off = ywoff(row, c4, 2048);
                pack_split4(y4, Y3h + off, Y3l + off);
            }
        }
        __syncthreads();
    }

    // ---- trailing GEMM3(nc=1) ----
    __builtin_amdgcn_s_setprio(1);
    #pragma unroll
    for (int kt = 0; kt < 4; ++kt) {
        bf16x8 a0[2], a1[2];
        #pragma unroll
        for (int mt = 0; mt < 2; ++mt) {
            int aoff = (wm*2 + mt) * 2048 + kt * 512 + lswz * 8;
            a0[mt] = *(const bf16x8*)(Y3h + aoff);
            a1[mt] = *(const bf16x8*)(Y3l + aoff);
        }
        #pragma unroll
        for (int nt = 0; nt < 2; ++nt) {
            int woff = (nt*4 + wn) * 4096 + (1*4 + kt) * 512 + lane * 8;
            bf16x8 wh = *(const bf16x8*)(wext + W3H + woff);
            bf16x8 wl = *(const bf16x8*)(wext + W3L + woff);
            #pragma unroll
            for (int mt = 0; mt < 2; ++mt) {
                MFMA3(acc3[mt][nt], a0[mt], a1[mt], wh, wl);
            }
        }
    }
    __builtin_amdgcn_s_setprio(0);

    // ---------------- pool: column sums of relu(acc3 + b3) -----------------
    #pragma unroll
    for (int nt = 0; nt < 2; ++nt) {
        int g_t = nt*4 + wn;
        float bv = b3[g_t*16 + l15];
        float cs = 0.f;
        #pragma unroll
        for (int mt = 0; mt < 2; ++mt)
        #pragma unroll
        for (int r = 0; r < 4; ++r) {
            int gr = r0 + (wm*2 + mt)*16 + lg*4 + r;
            if (gr < NN) cs += fmaxf(acc3[mt][nt][r] + bv, 0.f);
        }
        cs += __shfl_xor(cs, 16);
        cs += __shfl_xor(cs, 32);
        if (lane < 16) atomicAdd(&pool[g_t*16 + lane], cs);
    }
    __syncthreads();
    if (tid < 128) partial[((size_t)b * 8 + rt) * 128 + tid] = pool[tid];
}

// ---------------------------------------------------------------------------
// wconv: W fp32 [K][N] -> bf16 hi/lo planes, fragment layout (unswizzled)
// ---------------------------------------------------------------------------
__global__ __launch_bounds__(256) void wconv(
    const float* __restrict__ W1, const float* __restrict__ W2,
    const float* __restrict__ W3, ushort_t* __restrict__ wext)
{
    int i = blockIdx.x * 256 + threadIdx.x;
    float w; int off_h, off_l, idx;
    if (i < 8192) {                       // W1: K=64,  N=128
        int k = i >> 7, n = i & 127;
        w = W1[i]; idx = frag_off(n, k, 1024);  off_h = W1H; off_l = W1L;
    } else if (i < 40960) {               // W2: K=128, N=256
        int j = i - 8192;
        int k = j >> 8, n = j & 255;
        w = W2[j]; idx = frag_off(n, k, 2048);  off_h = W2H; off_l = W2L;
    } else if (i < 73728) {               // W3: K=256, N=128
        int j = i - 40960;
        int k = j >> 7, n = j & 127;
        w = W3[j]; idx = frag_off(n, k, 4096);  off_h = W3H; off_l = W3L;
    } else return;
    __hip_bfloat16 hb = __float2bfloat16(w);
    float hf = __bfloat162float(hb);
    __hip_bfloat16 lb = __float2bfloat16(w - hf);
    wext[off_h + idx] = *(ushort_t*)&hb;
    wext[off_l + idx] = *(ushort_t*)&lb;
}

// ---------------------------------------------------------------------------
// head: gf = mean-pool reduce; features = relu(gf@Wf+bf); out = feats@Wc+bc
// ---------------------------------------------------------------------------
__global__ __launch_bounds__(512) void head_kernel(
    const float* __restrict__ partial, const float* __restrict__ Wf,
    const float* __restrict__ bf, const float* __restrict__ Wc,
    const float* __restrict__ bc, float* __restrict__ dout)
{
    __shared__ float gfs[128];
    __shared__ float feats[512];
    int b = blockIdx.x, t = threadIdx.x;
    if (t < 128) {
        const float* p = partial + (size_t)b * (8 * 128);
        float s = 0.f;
        #pragma unroll
        for (int tt = 0; tt < 8; ++tt) s += p[tt * 128 + t];
        s *= (1.0f / 468.0f);
        gfs[t] = s;
        dout[65792 + b * 128 + t] = s;       // graph_features
    }
    __syncthreads();
    float a = bf[t];
    for (int k = 0; k < 128; ++k) a += gfs[k] * Wf[k * 512 + t];
    a = fmaxf(a, 0.f);
    dout[256 + b * 512 + t] = a;             // features
    feats[t] = a;
    __syncthreads();
    if (t < 64) {
        float s0 = 0.f, s1 = 0.f;
        for (int c = t; c < 512; c += 64) {
            float f = feats[c];
            s0 += f * Wc[c * 2 + 0];
            s1 += f * Wc[c * 2 + 1];
        }
        #pragma unroll
        for (int off = 32; off; off >>= 1) {
            s0 += __shfl_down(s0, off);
            s1 += __shfl_down(s1, off);
        }
        if (t == 0) {
            dout[b * 2 + 0] = s0 + bc[0];
            dout[b * 2 + 1] = s1 + bc[1];
        }
    }
}

// ---------------------------------------------------------------------------
extern "C" void kernel_launch(void* const* d_in, const int* in_sizes, int n_in,
                              void* d_out, int out_size, void* d_ws, size_t ws_size,
                              hipStream_t stream)
{
    const float* landmarks = (const float*)d_in[0];
    const float* W_enc     = (const float*)d_in[1];
    const float* b_enc     = (const float*)d_in[2];
    const float* W1        = (const float*)d_in[3];
    const float* b1        = (const float*)d_in[4];
    const float* W2        = (const float*)d_in[5];
    const float* b2        = (const float*)d_in[6];
    const float* W3        = (const float*)d_in[7];
    const float* b3        = (const float*)d_in[8];
    const float* W_fus     = (const float*)d_in[9];
    const float* b_fus     = (const float*)d_in[10];
    const float* W_cls     = (const float*)d_in[11];
    const float* b_cls     = (const float*)d_in[12];
    float* out = (float*)d_out;

    char* ws = (char*)d_ws;
    ushort_t* wext = (ushort_t*)(ws + 0);        // 294,912 B
    float* partial = (float*)(ws + 294912);      // 524,288 B

    wconv<<<288, 256, 0, stream>>>(W1, W2, W3, wext);
    fused<<<dim3(8, 128), 512, 0, stream>>>(
        landmarks, wext, W_enc, b_enc, b1, b2, b3, partial);
    head_kernel<<<128, 512, 0, stream>>>(partial, W_fus, b_fus, W_cls, b_cls, out);
}

// Round 17
// 66.771 us; speedup vs baseline: 2.7063x; 1.0422x over previous
//
#include <hip/hip_runtime.h>
#include <hip/hip_bf16.h>

typedef __bf16 bf16x8 __attribute__((ext_vector_type(8)));
typedef float  f32x4  __attribute__((ext_vector_type(4)));
typedef unsigned short ushort_t;

#define NN 468

// wext element offsets (ushort), fragment-major planes (NOT swizzled)
#define W1H 0
#define W1L 8192
#define W2H 16384
#define W2L 49152
#define W3H 81920
#define W3L 114688

// ---- LDS layout (64-row tile, hand-overlaid; total 78,752 B -> 2 blk/CU) --
// X0 [118][68]f32 = 32096  @0      (enc..band1)
// X1 [100][68]f32 = 27200  @0      (epi1..band2)
// X2 [82][132]f32 = 43296  @0      (epi2..band3)
// Y1  2 x 14336B           @32096  (band1..GEMM1)   [32096,60768)
// Y2  2 x 24576B (full K)  @27200  (band2..GEMM2)   [27200,76352)
// Y3  2 x 16384B           @43296  (band3..GEMM3)   [43296,76064)
// lmst 1416B @76352 | dtab 472B @77768 | pool 512B @78240
// Pairwise-live: {X0,Y1} {X1,Y2} {X2,Y3} all disjoint; Y overlaps are
// time-separated by the phase barriers (Y1 dead at band2, Y2 dead at epi2).
#define L_Y1   32096
#define L_Y2   27200
#define L_Y3   43296
#define L_LM   76352
#define L_DTAB 77768
#define L_POOL 78240

#define MFMA3(d, ah, al, wh, wl)                                        \
    d = __builtin_amdgcn_mfma_f32_16x16x32_bf16(ah, wh, d, 0, 0, 0);    \
    d = __builtin_amdgcn_mfma_f32_16x16x32_bf16(ah, wl, d, 0, 0, 0);    \
    d = __builtin_amdgcn_mfma_f32_16x16x32_bf16(al, wh, d, 0, 0, 0);

// ---------------------------------------------------------------------------
__device__ __forceinline__ void pack_split4(const float* y,
                                            ushort_t* hdst, ushort_t* ldst) {
    ushort_t h[4], l[4];
    #pragma unroll
    for (int j = 0; j < 4; ++j) {
        __hip_bfloat16 hb = __float2bfloat16(y[j]);
        float hf = __bfloat162float(hb);
        __hip_bfloat16 lb = __float2bfloat16(y[j] - hf);
        h[j] = *(ushort_t*)&hb; l[j] = *(ushort_t*)&lb;
    }
    uint2 hv = make_uint2((unsigned)h[0] | ((unsigned)h[1] << 16),
                          (unsigned)h[2] | ((unsigned)h[3] << 16));
    uint2 lv = make_uint2((unsigned)l[0] | ((unsigned)l[1] << 16),
                          (unsigned)l[2] | ((unsigned)l[3] << 16));
    *(uint2*)hdst = hv;
    *(uint2*)ldst = lv;
}

// unswizzled fragment offset (W planes in global memory)
__device__ __forceinline__ int frag_off(int r, int k, int K16) {
    return (r >> 4) * K16 + (k >> 5) * 512 + ((k >> 3) & 3) * 128
         + (r & 15) * 8 + (k & 7);
}

// swizzled Y-plane offset (LDS): unit' = q*16 + ((r ^ 2q) & 15)
__device__ __forceinline__ int ywoff(int r, int k4, int K16) {
    int q = (k4 >> 3) & 3;
    int u = q * 16 + (((r & 15) ^ (q << 1)) & 15);
    return (r >> 4) * K16 + (k4 >> 5) * 512 + u * 8 + (k4 & 7);
}

// ---------------------------------------------------------------------------
// fused: full 3-layer GCN chain for one (64-row tile, batch) in LDS.
// 512 threads = 8 waves (wm = w&1 over m, wn = w>>1 over n).
// Frames (dtab[t] = dinv(r0-27+t), t<118):
//   X0 row l0 : gr = r0-27+l0  (0..117)
//   Y1/X1 lr1 : gr = r0-18+lr1 (0..99, Y1 padded to 112 = 7 tiles)
//   Y2/X2 lr2 : gr = r0-9+lr2  (0..81, Y2 padded to 96 = 6 tiles)
//   Y3    lr3 : gr = r0+lr3    (0..63, 4 tiles)
// KEY vs R15: Y2 holds FULL K=128, so GEMM2 runs as one phase AFTER acc1
// dies — no acc1+acc2 register coexistence (R15 spilled 47MB scratch).
// launch_bounds(512,4): cap 128 regs — NEVER raise min-waves (R10/R13 spill).
// ---------------------------------------------------------------------------
__global__ __launch_bounds__(512, 4) void fused(
    const float* __restrict__ Lm, const ushort_t* __restrict__ wext,
    const float* __restrict__ We, const float* __restrict__ be,
    const float* __restrict__ b1, const float* __restrict__ b2,
    const float* __restrict__ b3, float* __restrict__ partial)
{
    __shared__ __align__(16) char lds[78752];
    float*    X    = (float*)(lds);            // X0 / X1 / X2 overlaid
    ushort_t* Y1h  = (ushort_t*)(lds + L_Y1);  ushort_t* Y1l = Y1h + 7168;
    ushort_t* Y2h  = (ushort_t*)(lds + L_Y2);  ushort_t* Y2l = Y2h + 12288;
    ushort_t* Y3h  = (ushort_t*)(lds + L_Y3);  ushort_t* Y3l = Y3h + 8192;
    float*    lmst = (float*)(lds + L_LM);
    float*    dtab = (float*)(lds + L_DTAB);
    float*    pool = (float*)(lds + L_POOL);

    const int tid  = threadIdx.x;
    const int lane = tid & 63;
    const int wave = tid >> 6;                 // 0..7
    const int wm = wave & 1, wn = wave >> 1;   // wn in 0..3
    const int l15 = lane & 15, lg = lane >> 4;
    const int lswz = (lane & 48) + (((lane & 15) ^ ((lane >> 4) << 1)) & 15);
    const int rt = blockIdx.x, b = blockIdx.y;
    const int r0 = rt * 64;

    // ---------------- stage: dinv table, landmarks, pool init -------------
    if (tid < 118) {
        int ri = r0 - 27 + tid;
        float dv = 0.f;
        if (ri >= 0 && ri < NN) {
            int lo = ri - 9; if (lo < 0) lo = 0;
            int hi = ri + 9; if (hi > NN - 1) hi = NN - 1;
            dv = 1.0f / sqrtf((float)(hi - lo + 1));
        }
        dtab[tid] = dv;
    }
    if (tid < 354) {
        int g = (r0 - 27) * 3 + tid;
        lmst[tid] = (g >= 0 && g < NN * 3) ? Lm[(size_t)b * (NN * 3) + g] : 0.f;
    }
    if (tid < 128) pool[tid] = 0.f;
    __syncthreads();

    // ---------------- enc: X0[118][68] = enc(row) * dinv -------------------
    {
        const int c = tid & 63;
        const float w0 = We[c], w1 = We[64 + c], w2 = We[128 + c], bk = be[c];
        for (int l0 = tid >> 6; l0 < 118; l0 += 8) {
            float x = bk + lmst[l0*3]*w0 + lmst[l0*3+1]*w1 + lmst[l0*3+2]*w2;
            X[l0 * 68 + c] = x * dtab[l0];
        }
    }
    __syncthreads();    // X0 ready; lmst dead

    // ---------------- band1: X0 -> Y1 [100 rows][64], pad to 112 -----------
    {
        const int c4 = (tid & 15) << 2;
        const int base = (tid >> 4) * 4;       // 32 groups x 4 rows
        if (base < 100) {
            f32x4 ws = {};
            #pragma unroll
            for (int d = 0; d < 19; ++d)
                ws += *(const f32x4*)(X + (base + d) * 68 + c4);
            #pragma unroll
            for (int rr = 0; rr < 4; ++rr) {
                int row = base + rr;
                if (rr) ws += *(const f32x4*)(X + (row + 18) * 68 + c4)
                            - *(const f32x4*)(X + (row - 1)  * 68 + c4);
                float dv = dtab[row + 9];
                float y4[4] = {ws[0]*dv, ws[1]*dv, ws[2]*dv, ws[3]*dv};
                int off = ywoff(row, c4, 1024);
                pack_split4(y4, Y1h + off, Y1l + off);
            }
        } else if (base < 112) {               // zero pad rows 100..111
            float z4[4] = {0.f, 0.f, 0.f, 0.f};
            #pragma unroll
            for (int rr = 0; rr < 4; ++rr) {
                int row = base + rr;
                if (row < 112) {
                    int off = ywoff(row, c4, 1024);
                    pack_split4(z4, Y1h + off, Y1l + off);
                }
            }
        }
    }
    __syncthreads();

    // ---------------- GEMM1: Y1(7 tiles) @ W1 ------------------------------
    // m: t = wm*4+mt clamp 6 (dup within-wave, benign); n: ntile = nt*4+wn
    f32x4 acc1[4][2] = {};
    __builtin_amdgcn_s_setprio(1);
    #pragma unroll
    for (int kt = 0; kt < 2; ++kt) {
        bf16x8 a[4][2];
        #pragma unroll
        for (int mt = 0; mt < 4; ++mt) {
            int t = wm*4 + mt; if (t > 6) t = 6;
            int off = t * 1024 + kt * 512 + lswz * 8;
            a[mt][0] = *(const bf16x8*)(Y1h + off);
            a[mt][1] = *(const bf16x8*)(Y1l + off);
        }
        #pragma unroll
        for (int nt = 0; nt < 2; ++nt) {
            int woff = (nt*4 + wn) * 1024 + kt * 512 + lane * 8;
            bf16x8 wh = *(const bf16x8*)(wext + W1H + woff);
            bf16x8 wl = *(const bf16x8*)(wext + W1L + woff);
            #pragma unroll
            for (int mt = 0; mt < 4; ++mt) {
                MFMA3(acc1[mt][nt], a[mt][0], a[mt][1], wh, wl);
            }
        }
    }
    __builtin_amdgcn_s_setprio(0);
    // no barrier needed: epi1(0) writes X1 (region disjoint from Y1)

    // ------- kc loop: epi1(kc) -> X1 -> band2(kc) -> Y2 cols kc*64.. -------
    #pragma unroll
    for (int kc = 0; kc < 2; ++kc) {
        // epi1(kc): acc1[:,kc] -> X1[100][68] premult
        #pragma unroll
        for (int mt = 0; mt < 4; ++mt) {
            int t = wm*4 + mt; if (t > 6) t = 6;
            int gcol = (kc*4 + wn)*16 + l15;
            int cl   = wn*16 + l15;
            float bv = b1[gcol];
            #pragma unroll
            for (int r = 0; r < 4; ++r) {
                int lr1 = t*16 + lg*4 + r;
                if (lr1 < 100)
                    X[lr1*68 + cl] =
                        dtab[lr1 + 9] * fmaxf(acc1[mt][kc][r] + bv, 0.f);
            }
        }
        __syncthreads();   // X1 ready; (kc=0) also fences Y1 reads vs Y2 writes

        // band2(kc): X1 -> Y2 [82 rows][k-cols kc*64..+64), pad rows to 96
        {
            const int c4   = (tid & 15) << 2;
            const int base = (tid >> 4) * 3;   // 32 groups x 3 rows = 96
            f32x4 ws = {};
            if (base < 82) {
                #pragma unroll
                for (int d = 0; d < 19; ++d)
                    ws += *(const f32x4*)(X + (base + d) * 68 + c4);
            }
            #pragma unroll
            for (int rr = 0; rr < 3; ++rr) {
                int row = base + rr;
                if (row < 96) {
                    float y4[4] = {0.f, 0.f, 0.f, 0.f};
                    if (row < 82) {
                        if (rr) ws += *(const f32x4*)(X + (row + 18) * 68 + c4)
                                    - *(const f32x4*)(X + (row - 1)  * 68 + c4);
                        float dv = dtab[row + 18];
                        y4[0] = ws[0]*dv; y4[1] = ws[1]*dv;
                        y4[2] = ws[2]*dv; y4[3] = ws[3]*dv;
                    }
                    int off = ywoff(row, kc*64 + c4, 2048);
                    pack_split4(y4, Y2h + off, Y2l + off);
                }
            }
        }
        __syncthreads();   // Y2 chunk ready; X1 reads done (epi1(1) may rewrite)
    }

    // ---------------- GEMM2: Y2(6 tiles, K=128) @ W2 — one fat phase -------
    // acc1 is DEAD here: no accumulator coexistence, no spill.
    f32x4 acc2[3][4] = {};
    __builtin_amdgcn_s_setprio(1);
    #pragma unroll
    for (int kt = 0; kt < 4; ++kt) {
        bf16x8 a[3][2];
        #pragma unroll
        for (int mt = 0; mt < 3; ++mt) {
            int off = (wm*3 + mt) * 2048 + kt * 512 + lswz * 8;
            a[mt][0] = *(const bf16x8*)(Y2h + off);
            a[mt][1] = *(const bf16x8*)(Y2l + off);
        }
        #pragma unroll
        for (int nt = 0; nt < 4; ++nt) {
            int woff = (nt*4 + wn) * 2048 + kt * 512 + lane * 8;
            bf16x8 wh = *(const bf16x8*)(wext + W2H + woff);
            bf16x8 wl = *(const bf16x8*)(wext + W2L + woff);
            #pragma unroll
            for (int mt = 0; mt < 3; ++mt) {
                MFMA3(acc2[mt][nt], a[mt][0], a[mt][1], wh, wl);
            }
        }
    }
    __builtin_amdgcn_s_setprio(0);
    __syncthreads();   // all Y2 reads done before epi2(0) writes X2 (overlap!)

    // ------- nc loop: [GEMM3(nc-1) ∥] epi2 -> X2 -> band3 -> Y3 -> GEMM3 ---
    f32x4 acc3[2][2] = {};
    #pragma unroll
    for (int nc = 0; nc < 2; ++nc) {
        if (nc == 1) {
            __builtin_amdgcn_s_setprio(1);
            #pragma unroll
            for (int kt = 0; kt < 4; ++kt) {
                bf16x8 a0[2], a1[2];
                #pragma unroll
                for (int mt = 0; mt < 2; ++mt) {
                    int aoff = (wm*2 + mt) * 2048 + kt * 512 + lswz * 8;
                    a0[mt] = *(const bf16x8*)(Y3h + aoff);
                    a1[mt] = *(const bf16x8*)(Y3l + aoff);
                }
                #pragma unroll
                for (int nt = 0; nt < 2; ++nt) {
                    int woff = (nt*4 + wn) * 4096 + (0*4 + kt) * 512 + lane * 8;
                    bf16x8 wh = *(const bf16x8*)(wext + W3H + woff);
                    bf16x8 wl = *(const bf16x8*)(wext + W3L + woff);
                    #pragma unroll
                    for (int mt = 0; mt < 2; ++mt) {
                        MFMA3(acc3[mt][nt], a0[mt], a1[mt], wh, wl);
                    }
                }
            }
            __builtin_amdgcn_s_setprio(0);
        }
        // epi2(nc): acc2 n-chunk -> X2[82][132] premult
        #pragma unroll
        for (int mt = 0; mt < 3; ++mt)
        #pragma unroll
        for (int q = 0; q < 2; ++q) {
            int gcol = ((nc*2 + q)*4 + wn)*16 + l15;
            int cl   = (q*4 + wn)*16 + l15;
            float bv = b2[gcol];
            #pragma unroll
            for (int r = 0; r < 4; ++r) {
                int lr2 = (wm*3 + mt)*16 + lg*4 + r;
                if (lr2 < 82)
                    X[lr2*132 + cl] =
                        dtab[lr2 + 18] * fmaxf(acc2[mt][nc*2 + q][r] + bv, 0.f);
            }
        }
        __syncthreads();

        // band3(nc): X2 -> Y3 [64 rows][128]
        {
            const int c4   = (tid & 31) << 2;  // 128 cols
            const int base = (tid >> 5) * 4;   // 16 groups x 4 rows
            f32x4 ws = {};
            #pragma unroll
            for (int d = 0; d < 19; ++d)
                ws += *(const f32x4*)(X + (base + d) * 132 + c4);
            #pragma unroll
            for (int rr = 0; rr < 4; ++rr) {
                int row = base + rr;
                if (rr) ws += *(const f32x4*)(X + (row + 18) * 132 + c4)
                            - *(const f32x4*)(X + (row - 1)  * 132 + c4);
                float dv = dtab[row + 27];
                float y4[4] = {ws[0]*dv, ws[1]*dv, ws[2]*dv, ws[3]*dv};
                int off = ywoff(row, c4, 2048);
                pack_split4(y4, Y3h + off, Y3l + off);
            }
        }
        __syncthreads();
    }

    // ---- trailing GEMM3(nc=1) ----
    __builtin_amdgcn_s_setprio(1);
    #pragma unroll
    for (int kt = 0; kt < 4; ++kt) {
        bf16x8 a0[2], a1[2];
        #pragma unroll
        for (int mt = 0; mt < 2; ++mt) {
            int aoff = (wm*2 + mt) * 2048 + kt * 512 + lswz * 8;
            a0[mt] = *(const bf16x8*)(Y3h + aoff);
            a1[mt] = *(const bf16x8*)(Y3l + aoff);
        }
        #pragma unroll
        for (int nt = 0; nt < 2; ++nt) {
            int woff = (nt*4 + wn) * 4096 + (1*4 + kt) * 512 + lane * 8;
            bf16x8 wh = *(const bf16x8*)(wext + W3H + woff);
            bf16x8 wl = *(const bf16x8*)(wext + W3L + woff);
            #pragma unroll
            for (int mt = 0; mt < 2; ++mt) {
                MFMA3(acc3[mt][nt], a0[mt], a1[mt], wh, wl);
            }
        }
    }
    __builtin_amdgcn_s_setprio(0);

    // ---------------- pool: column sums of relu(acc3 + b3) -----------------
    #pragma unroll
    for (int nt = 0; nt < 2; ++nt) {
        int g_t = nt*4 + wn;
        float bv = b3[g_t*16 + l15];
        float cs = 0.f;
        #pragma unroll
        for (int mt = 0; mt < 2; ++mt)
        #pragma unroll
        for (int r = 0; r < 4; ++r) {
            int gr = r0 + (wm*2 + mt)*16 + lg*4 + r;
            if (gr < NN) cs += fmaxf(acc3[mt][nt][r] + bv, 0.f);
        }
        cs += __shfl_xor(cs, 16);
        cs += __shfl_xor(cs, 32);
        if (lane < 16) atomicAdd(&pool[g_t*16 + lane], cs);
    }
    __syncthreads();
    if (tid < 128) partial[((size_t)b * 8 + rt) * 128 + tid] = pool[tid];
}

// ---------------------------------------------------------------------------
// wconv: W fp32 [K][N] -> bf16 hi/lo planes, fragment layout (unswizzled)
// ---------------------------------------------------------------------------
__global__ __launch_bounds__(256) void wconv(
    const float* __restrict__ W1, const float* __restrict__ W2,
    const float* __restrict__ W3, ushort_t* __restrict__ wext)
{
    int i = blockIdx.x * 256 + threadIdx.x;
    float w; int off_h, off_l, idx;
    if (i < 8192) {                       // W1: K=64,  N=128
        int k = i >> 7, n = i & 127;
        w = W1[i]; idx = frag_off(n, k, 1024);  off_h = W1H; off_l = W1L;
    } else if (i < 40960) {               // W2: K=128, N=256
        int j = i - 8192;
        int k = j >> 8, n = j & 255;
        w = W2[j]; idx = frag_off(n, k, 2048);  off_h = W2H; off_l = W2L;
    } else if (i < 73728) {               // W3: K=256, N=128
        int j = i - 40960;
        int k = j >> 7, n = j & 127;
        w = W3[j]; idx = frag_off(n, k, 4096);  off_h = W3H; off_l = W3L;
    } else return;
    __hip_bfloat16 hb = __float2bfloat16(w);
    float hf = __bfloat162float(hb);
    __hip_bfloat16 lb = __float2bfloat16(w - hf);
    wext[off_h + idx] = *(ushort_t*)&hb;
    wext[off_l + idx] = *(ushort_t*)&lb;
}

// ---------------------------------------------------------------------------
// head: gf = mean-pool reduce; features = relu(gf@Wf+bf); out = feats@Wc+bc
// ---------------------------------------------------------------------------
__global__ __launch_bounds__(512) void head_kernel(
    const float* __restrict__ partial, const float* __restrict__ Wf,
    const float* __restrict__ bf, const float* __restrict__ Wc,
    const float* __restrict__ bc, float* __restrict__ dout)
{
    __shared__ float gfs[128];
    __shared__ float feats[512];
    int b = blockIdx.x, t = threadIdx.x;
    if (t < 128) {
        const float* p = partial + (size_t)b * (8 * 128);
        float s = 0.f;
        #pragma unroll
        for (int tt = 0; tt < 8; ++tt) s += p[tt * 128 + t];
        s *= (1.0f / 468.0f);
        gfs[t] = s;
        dout[65792 + b * 128 + t] = s;       // graph_features
    }
    __syncthreads();
    float a = bf[t];
    for (int k = 0; k < 128; ++k) a += gfs[k] * Wf[k * 512 + t];
    a = fmaxf(a, 0.f);
    dout[256 + b * 512 + t] = a;             // features
    feats[t] = a;
    __syncthreads();
    if (t < 64) {
        float s0 = 0.f, s1 = 0.f;
        for (int c = t; c < 512; c += 64) {
            float f = feats[c];
            s0 += f * Wc[c * 2 + 0];
            s1 += f * Wc[c * 2 + 1];
        }
        #pragma unroll
        for (int off = 32; off; off >>= 1) {
            s0 += __shfl_down(s0, off);
            s1 += __shfl_down(s1, off);
        }
        if (t == 0) {
            dout[b * 2 + 0] = s0 + bc[0];
            dout[b * 2 + 1] = s1 + bc[1];
        }
    }
}

// ---------------------------------------------------------------------------
extern "C" void kernel_launch(void* const* d_in, const int* in_sizes, int n_in,
                              void* d_out, int out_size, void* d_ws, size_t ws_size,
                              hipStream_t stream)
{
    const float* landmarks = (const float*)d_in[0];
    const float* W_enc     = (const float*)d_in[1];
    const float* b_enc     = (const float*)d_in[2];
    const float* W1        = (const float*)d_in[3];
    const float* b1        = (const float*)d_in[4];
    const float* W2        = (const float*)d_in[5];
    const float* b2        = (const float*)d_in[6];
    const float* W3        = (const float*)d_in[7];
    const float* b3        = (const float*)d_in[8];
    const float* W_fus     = (const float*)d_in[9];
    const float* b_fus     = (const float*)d_in[10];
    const float* W_cls     = (const float*)d_in[11];
    const float* b_cls     = (const float*)d_in[12];
    float* out = (float*)d_out;

    char* ws = (char*)d_ws;
    ushort_t* wext = (ushort_t*)(ws + 0);        // 294,912 B
    float* partial = (float*)(ws + 294912);      // 524,288 B

    wconv<<<288, 256, 0, stream>>>(W1, W2, W3, wext);
    fused<<<dim3(8, 128), 512, 0, stream>>>(
        landmarks, wext, W_enc, b_enc, b1, b2, b3, partial);
    head_kernel<<<128, 512, 0, stream>>>(partial, W_fus, b_fus, W_cls, b_cls, out);
}